// Round 14
// baseline (111.140 us; speedup 1.0000x reference)
//
#include <hip/hip_runtime.h>

namespace {
constexpr int NB = 128;
constexpr int NR = 512;
constexpr int ND = 256;
constexpr int NA = 14;
constexpr int NT = 20;

using short8 = __attribute__((ext_vector_type(8))) short;
using f32x4  = __attribute__((ext_vector_type(4))) float;

// workspace: folded M matrices in A-fragment layout, then nothing else needed
constexpr size_t M_US      = (size_t)NT * 16 * 64 * 8;   // 163,840 ushort
constexpr size_t WS_NEEDED = M_US * 2;                   // 327,680 bytes

__device__ __forceinline__ unsigned short f2bf(float f) {
    unsigned int u = __float_as_uint(f);
    u = (u + 0x7FFFu + ((u >> 16) & 1u)) >> 16;           // RNE
    return (unsigned short)u;
}
__device__ __forceinline__ short8 cvt8(const float* p) {
    short8 r;
#pragma unroll
    for (int j = 0; j < 8; ++j) r[j] = (short)f2bf(p[j]);
    return r;
}
// bank swizzle for fstc v-index (write AND read); stride 260 == 4 mod 32
__device__ __forceinline__ int vswz(int v) { return v ^ (((v >> 5) & 3) << 3); }
}

// ---- fold kernel: M_t = Wh[t,1] * Wh[t,0] * W0[t]  (one block per type) ----
// 256 threads = 4 waves; wave w owns m-tiles mt = 4w..4w+3 (v = 64w..64w+64).
// Both MFMA operand frags use layout elem[outdim = lane&15][k = (lane>>4)*8+j]
// (verified by the r3-r13 production GEMM); C: col=lane&15, row=(lane>>4)*4+jj.
__global__ __launch_bounds__(256) void fold_M(
    const float* __restrict__ W0, const float* __restrict__ Wh,
    unsigned short* __restrict__ wsM)
{
    const int t = blockIdx.x, tid = threadIdx.x, lane = tid & 63, w = tid >> 6;
    __shared__ __align__(16) unsigned short T1T[16 * 264];
    __shared__ __align__(16) unsigned short MT[16 * 264];

    // B-frags of W0^T: lane holds W0[u][a], a = lane&15 (a>=14 -> 0)
    short8 bw0[8];
    {
        const int a = lane & 15;
#pragma unroll
        for (int kt = 0; kt < 8; ++kt) {
            unsigned short o[8];
#pragma unroll
            for (int j = 0; j < 8; ++j) {
                const int u = kt * 32 + (lane >> 4) * 8 + j;
                o[j] = (a < NA) ? f2bf(W0[((size_t)t * ND + u) * NA + a]) : (unsigned short)0;
            }
            short8 v;
#pragma unroll
            for (int j = 0; j < 8; ++j) v[j] = (short)o[j];
            bw0[kt] = v;
        }
    }

    // GEMM1: T1 = Wh[t,0] * W0   (256x14, K=256)
    f32x4 acc[4];
#pragma unroll
    for (int mi = 0; mi < 4; ++mi) acc[mi] = f32x4{0.f, 0.f, 0.f, 0.f};
#pragma unroll 1
    for (int kt = 0; kt < 8; ++kt) {
#pragma unroll
        for (int mi = 0; mi < 4; ++mi) {
            const int v = (w * 4 + mi) * 16 + (lane & 15);
            const float* src = Wh + (((size_t)(t * 2 + 0) * ND + v) * ND) + kt * 32 + (lane >> 4) * 8;
            acc[mi] = __builtin_amdgcn_mfma_f32_16x16x32_bf16(cvt8(src), bw0[kt], acc[mi], 0, 0, 0);
        }
    }
#pragma unroll
    for (int mi = 0; mi < 4; ++mi) {
        const int v0 = (w * 4 + mi) * 16 + (lane >> 4) * 4;
        const int a  = lane & 15;
        const unsigned lo = (unsigned)f2bf(acc[mi][0]) | ((unsigned)f2bf(acc[mi][1]) << 16);
        const unsigned hi = (unsigned)f2bf(acc[mi][2]) | ((unsigned)f2bf(acc[mi][3]) << 16);
        *reinterpret_cast<uint2*>(&T1T[a * 264 + v0]) = make_uint2(lo, hi);
    }
    __syncthreads();

    // GEMM2: M = Wh[t,1] * T1   (256x14, K=256)
#pragma unroll
    for (int mi = 0; mi < 4; ++mi) acc[mi] = f32x4{0.f, 0.f, 0.f, 0.f};
#pragma unroll 1
    for (int kt = 0; kt < 8; ++kt) {
        const short8 bf = *reinterpret_cast<const short8*>(&T1T[(lane & 15) * 264 + kt * 32 + (lane >> 4) * 8]);
#pragma unroll
        for (int mi = 0; mi < 4; ++mi) {
            const int v = (w * 4 + mi) * 16 + (lane & 15);
            const float* src = Wh + (((size_t)(t * 2 + 1) * ND + v) * ND) + kt * 32 + (lane >> 4) * 8;
            acc[mi] = __builtin_amdgcn_mfma_f32_16x16x32_bf16(cvt8(src), bf, acc[mi], 0, 0, 0);
        }
    }
#pragma unroll
    for (int mi = 0; mi < 4; ++mi) {
        const int v0 = (w * 4 + mi) * 16 + (lane >> 4) * 4;
        const int a  = lane & 15;
        const unsigned lo = (unsigned)f2bf(acc[mi][0]) | ((unsigned)f2bf(acc[mi][1]) << 16);
        const unsigned hi = (unsigned)f2bf(acc[mi][2]) | ((unsigned)f2bf(acc[mi][3]) << 16);
        *reinterpret_cast<uint2*>(&MT[a * 264 + v0]) = make_uint2(lo, hi);
    }
    __syncthreads();

    // scatter M into A-fragment layout: lane holds M[v=mt*16+(l&15)][k=(l>>4)*8+j]
    for (int g = tid; g < 16 * 64; g += 256) {
        const int mt = g >> 6, l2 = g & 63;
        const int v = mt * 16 + (l2 & 15);
        unsigned short o[8];
#pragma unroll
        for (int j = 0; j < 8; ++j) {
            const int k = (l2 >> 4) * 8 + j;
            o[j] = (k < NA) ? MT[k * 264 + v] : (unsigned short)0;
        }
        uint4 pk;
        pk.x = o[0] | ((unsigned)o[1] << 16); pk.y = o[2] | ((unsigned)o[3] << 16);
        pk.z = o[4] | ((unsigned)o[5] << 16); pk.w = o[6] | ((unsigned)o[7] << 16);
        *reinterpret_cast<uint4*>(wsM + ((size_t)(t * 16 + mt) * 64 + l2) * 8) = pk;
    }
}

// ---- main kernel: h = M_t * delta ------------------------------------------
// 4096 blocks, 512 threads (8 waves). Block = (r = bid>>3, 16 batches).
// Wave w owns v in [32w,32w+32): acc[2][3], 6 MFMA total. M is 320KB global
// -> L2-resident on every XCD (no rmap needed). Then 2-pass transpose
// epilogue (r11-verified) + div-free coalesced nt stores. 3 barriers.
// LDS: dltT 3840 + fstc 24960 = 28.8KB -> 4 blocks/CU (32 waves).
__global__ __launch_bounds__(512, 4) void residues_main(
    const float* __restrict__ x, const unsigned short* __restrict__ wsM,
    const int* __restrict__ type_ids, const int* __restrict__ res_idx,
    float* __restrict__ out, int n_atoms)
{
    const int tid = threadIdx.x, lane = tid & 63, w = tid >> 6;
    const int r = blockIdx.x >> 3;
    const int b0 = (blockIdx.x & 7) * 16;
    const int ri = res_idx[r], t = type_ids[r];

    __shared__ __align__(16) unsigned short dltT[48 * 40];   // 3840 B
    __shared__ __align__(16) float fstc[24 * 260];           // 24960 B

    // A-frags of M (depend only on t): wave w -> m-tiles 2w, 2w+1
    short8 aM[2];
#pragma unroll
    for (int mi = 0; mi < 2; ++mi)
        aM[mi] = *reinterpret_cast<const short8*>(wsM + ((size_t)(t * 16 + w * 2 + mi) * 64 + lane) * 8);

    // ---- stage: dltT (bf16, K padded to 32) + pos_ca -----------------------
    {
        const int bl = tid >> 5, k = tid & 31;     // 512 tasks = 16 bl x 32 k
        const float* xb = x + (size_t)(b0 + bl) * n_atoms * 3;
        if (k < 16) {
            int atom = ri + k; if (atom > n_atoms - 1) atom = n_atoms - 1;
            const float* src  = xb + (size_t)atom * 3;
            const float* root = xb + (size_t)(ri + 1) * 3;
#pragma unroll
            for (int c = 0; c < 3; ++c)
                dltT[(bl * 3 + c) * 40 + k] = f2bf(src[c] - root[c]);
            if (k == 1) {
#pragma unroll
                for (int c = 0; c < 3; ++c)
                    out[((size_t)(b0 + bl) * NR + r) * 3 + c] = root[c];
            }
        } else {
#pragma unroll
            for (int c = 0; c < 3; ++c)
                dltT[(bl * 3 + c) * 40 + k] = 0;
        }
    }
    __syncthreads();                               // B1: dltT ready

    // ---- single GEMM: K=32 (zeros >=14 in BOTH operands kill clamp rows) ---
    f32x4 acc[2][3];
#pragma unroll
    for (int mi = 0; mi < 2; ++mi)
#pragma unroll
        for (int ni = 0; ni < 3; ++ni) acc[mi][ni] = f32x4{0.f, 0.f, 0.f, 0.f};
    {
        short8 bf[3];
#pragma unroll
        for (int ni = 0; ni < 3; ++ni)
            bf[ni] = *reinterpret_cast<const short8*>(&dltT[(ni * 16 + (lane & 15)) * 40 + (lane >> 4) * 8]);
#pragma unroll
        for (int mi = 0; mi < 2; ++mi)
#pragma unroll
            for (int ni = 0; ni < 3; ++ni)
                acc[mi][ni] = __builtin_amdgcn_mfma_f32_16x16x32_bf16(aM[mi], bf[ni], acc[mi][ni], 0, 0, 0);
    }

    // ---- epilogue: 2 column-half passes (r11-verified), nt f32x4 stores ----
    float* outh = out + (size_t)NB * NR * 3;
#pragma unroll 1
    for (int q = 0; q < 2; ++q) {
        // restage cols n in [24q,24q+24): fstc[nloc][vswz(v)], f32x4 aligned
#pragma unroll
        for (int mi = 0; mi < 2; ++mi)
#pragma unroll
            for (int ni = 0; ni < 3; ++ni) {
                const int n = ni * 16 + (lane & 15);
                const int nloc = n - 24 * q;
                if (nloc >= 0 && nloc < 24) {
                    const int vb = w * 32 + mi * 16 + (lane >> 4) * 4;
                    *reinterpret_cast<f32x4*>(&fstc[nloc * 260 + vswz(vb)]) = acc[mi][ni];
                }
            }
        __syncthreads();                           // fstc ready
        // store: wave w -> batch b0+8q+w, contiguous 768 floats
        {
            const size_t obase = ((size_t)(b0 + 8 * q + w) * NR + r) * (ND * 3);
#pragma unroll
            for (int i = 0; i < 3; ++i) {
                const int f0 = (lane + 64 * i) * 4;        // 0..764 step 4
                int v = f0 / 3;
                int c = f0 - v * 3;
                f32x4 o;
#pragma unroll
                for (int e = 0; e < 4; ++e) {
                    o[e] = fstc[(w * 3 + c) * 260 + vswz(v)];
                    ++c; if (c == 3) { c = 0; ++v; }
                }
                __builtin_nontemporal_store(o,
                    reinterpret_cast<f32x4*>(&outh[obase + f0]));
            }
        }
        if (q == 0) __syncthreads();               // fstc reads done before overwrite
    }
}

// ---- fallback (round-2 verified VALU kernel) if ws too small ---------------
__global__ __launch_bounds__(256, 3) void residues_fused_fb(
    const float* __restrict__ x, const float* __restrict__ W0,
    const float* __restrict__ Wh, const int* __restrict__ type_ids,
    const int* __restrict__ res_idx, float* __restrict__ out, int n_atoms)
{
    const int tid = threadIdx.x;
    const int r = blockIdx.x >> 4;
    const int b0 = (blockIdx.x & 15) * 8;
    const int ri = res_idx[r], t = type_ids[r];
    __shared__ float dlt[NA][24];
    __shared__ float hA[ND][24];
    __shared__ float hB[ND][24];
    for (int idx = tid; idx < 8 * NA * 3; idx += 256) {
        const int bb = idx / (NA * 3), rem = idx % (NA * 3);
        const int a = rem / 3, c = rem % 3, b = b0 + bb;
        int ca = ri + a; if (ca > n_atoms - 1) ca = n_atoms - 1;
        const float root = x[((size_t)b * n_atoms + (ri + 1)) * 3 + c];
        dlt[a][bb * 3 + c] = x[((size_t)b * n_atoms + ca) * 3 + c] - root;
        if (a == 0) out[((size_t)b * NR + r) * 3 + c] = root;
    }
    __syncthreads();
    {
        const float* w0row = W0 + ((size_t)t * ND + tid) * NA;
        float acc[24];
#pragma unroll
        for (int n = 0; n < 24; ++n) acc[n] = 0.f;
#pragma unroll
        for (int a = 0; a < NA; ++a) {
            const float wv = w0row[a];
#pragma unroll
            for (int n = 0; n < 24; ++n) acc[n] += wv * dlt[a][n];
        }
#pragma unroll
        for (int n = 0; n < 24; ++n) hA[tid][n] = acc[n];
    }
    __syncthreads();
    const float* whbase = Wh + (size_t)t * 2 * ND * ND;
#pragma unroll
    for (int l = 0; l < 2; ++l) {
        const float* wrow = whbase + ((size_t)l * ND + tid) * ND;
        const float (*hin)[24] = (l == 0) ? hA : hB;
        float (*hout)[24]      = (l == 0) ? hB : hA;
        float acc[24];
#pragma unroll
        for (int n = 0; n < 24; ++n) acc[n] = 0.f;
        for (int u = 0; u < ND; ++u) {
            const float wv = wrow[u];
#pragma unroll
            for (int n = 0; n < 24; ++n) acc[n] += wv * hin[u][n];
        }
#pragma unroll
        for (int n = 0; n < 24; ++n) hout[tid][n] = acc[n];
        __syncthreads();
    }
    float* outh = out + (size_t)NB * NR * 3;
#pragma unroll
    for (int bb = 0; bb < 8; ++bb) {
        const size_t base = ((size_t)((b0 + bb) * NR + r)) * (ND * 3);
#pragma unroll
        for (int it = 0; it < 3; ++it) {
            const int g = it * 256 + tid;
            outh[base + g] = hA[g / 3][bb * 3 + g % 3];
        }
    }
}

extern "C" void kernel_launch(void* const* d_in, const int* in_sizes, int n_in,
                              void* d_out, int out_size, void* d_ws, size_t ws_size,
                              hipStream_t stream) {
    const float* x        = (const float*)d_in[0];
    const float* W0       = (const float*)d_in[1];
    const float* Wh       = (const float*)d_in[2];
    const int*   type_ids = (const int*)d_in[3];
    const int*   res_idx  = (const int*)d_in[4];
    float* out = (float*)d_out;
    const int n_atoms = in_sizes[0] / (NB * 3);

    if (ws_size >= WS_NEEDED) {
        unsigned short* wsM = (unsigned short*)d_ws;
        fold_M<<<NT, 256, 0, stream>>>(W0, Wh, wsM);
        residues_main<<<NR * 8, 512, 0, stream>>>(x, wsM, type_ids, res_idx, out, n_atoms);
    } else {
        residues_fused_fb<<<NR * 16, 256, 0, stream>>>(x, W0, Wh, type_ids, res_idx, out, n_atoms);
    }
}

// Round 15
// 107.839 us; speedup vs baseline: 1.0306x; 1.0306x over previous
//
#include <hip/hip_runtime.h>

namespace {
constexpr int NB = 128;
constexpr int NR = 512;
constexpr int ND = 256;
constexpr int NA = 14;
constexpr int NT = 20;

using short8 = __attribute__((ext_vector_type(8))) short;
using f32x4  = __attribute__((ext_vector_type(4))) float;

// workspace: folded M matrices in A-fragment layout
constexpr size_t M_US      = (size_t)NT * 16 * 64 * 8;   // 163,840 ushort
constexpr size_t WS_NEEDED = M_US * 2;                   // 327,680 bytes

__device__ __forceinline__ unsigned short f2bf(float f) {
    unsigned int u = __float_as_uint(f);
    u = (u + 0x7FFFu + ((u >> 16) & 1u)) >> 16;           // RNE
    return (unsigned short)u;
}
__device__ __forceinline__ short8 cvt8(const float* p) {
    short8 r;
#pragma unroll
    for (int j = 0; j < 8; ++j) r[j] = (short)f2bf(p[j]);
    return r;
}
// bank swizzle for fstc v-index (write AND read); stride 260 == 4 mod 32
__device__ __forceinline__ int vswz(int v) { return v ^ (((v >> 5) & 3) << 3); }
}

// ---- fold kernel: M_t = Wh[t,1] * Wh[t,0] * W0[t]  (one block per type) ----
__global__ __launch_bounds__(256) void fold_M(
    const float* __restrict__ W0, const float* __restrict__ Wh,
    unsigned short* __restrict__ wsM)
{
    const int t = blockIdx.x, tid = threadIdx.x, lane = tid & 63, w = tid >> 6;
    __shared__ __align__(16) unsigned short T1T[16 * 264];
    __shared__ __align__(16) unsigned short MT[16 * 264];

    // B-frags of W0^T: lane holds W0[u][a], a = lane&15 (a>=14 -> 0)
    short8 bw0[8];
    {
        const int a = lane & 15;
#pragma unroll
        for (int kt = 0; kt < 8; ++kt) {
            unsigned short o[8];
#pragma unroll
            for (int j = 0; j < 8; ++j) {
                const int u = kt * 32 + (lane >> 4) * 8 + j;
                o[j] = (a < NA) ? f2bf(W0[((size_t)t * ND + u) * NA + a]) : (unsigned short)0;
            }
            short8 v;
#pragma unroll
            for (int j = 0; j < 8; ++j) v[j] = (short)o[j];
            bw0[kt] = v;
        }
    }

    // GEMM1: T1 = Wh[t,0] * W0   (256x14, K=256)
    f32x4 acc[4];
#pragma unroll
    for (int mi = 0; mi < 4; ++mi) acc[mi] = f32x4{0.f, 0.f, 0.f, 0.f};
#pragma unroll 1
    for (int kt = 0; kt < 8; ++kt) {
#pragma unroll
        for (int mi = 0; mi < 4; ++mi) {
            const int v = (w * 4 + mi) * 16 + (lane & 15);
            const float* src = Wh + (((size_t)(t * 2 + 0) * ND + v) * ND) + kt * 32 + (lane >> 4) * 8;
            acc[mi] = __builtin_amdgcn_mfma_f32_16x16x32_bf16(cvt8(src), bw0[kt], acc[mi], 0, 0, 0);
        }
    }
#pragma unroll
    for (int mi = 0; mi < 4; ++mi) {
        const int v0 = (w * 4 + mi) * 16 + (lane >> 4) * 4;
        const int a  = lane & 15;
        const unsigned lo = (unsigned)f2bf(acc[mi][0]) | ((unsigned)f2bf(acc[mi][1]) << 16);
        const unsigned hi = (unsigned)f2bf(acc[mi][2]) | ((unsigned)f2bf(acc[mi][3]) << 16);
        *reinterpret_cast<uint2*>(&T1T[a * 264 + v0]) = make_uint2(lo, hi);
    }
    __syncthreads();

    // GEMM2: M = Wh[t,1] * T1   (256x14, K=256)
#pragma unroll
    for (int mi = 0; mi < 4; ++mi) acc[mi] = f32x4{0.f, 0.f, 0.f, 0.f};
#pragma unroll 1
    for (int kt = 0; kt < 8; ++kt) {
        const short8 bf = *reinterpret_cast<const short8*>(&T1T[(lane & 15) * 264 + kt * 32 + (lane >> 4) * 8]);
#pragma unroll
        for (int mi = 0; mi < 4; ++mi) {
            const int v = (w * 4 + mi) * 16 + (lane & 15);
            const float* src = Wh + (((size_t)(t * 2 + 1) * ND + v) * ND) + kt * 32 + (lane >> 4) * 8;
            acc[mi] = __builtin_amdgcn_mfma_f32_16x16x32_bf16(cvt8(src), bf, acc[mi], 0, 0, 0);
        }
    }
#pragma unroll
    for (int mi = 0; mi < 4; ++mi) {
        const int v0 = (w * 4 + mi) * 16 + (lane >> 4) * 4;
        const int a  = lane & 15;
        const unsigned lo = (unsigned)f2bf(acc[mi][0]) | ((unsigned)f2bf(acc[mi][1]) << 16);
        const unsigned hi = (unsigned)f2bf(acc[mi][2]) | ((unsigned)f2bf(acc[mi][3]) << 16);
        *reinterpret_cast<uint2*>(&MT[a * 264 + v0]) = make_uint2(lo, hi);
    }
    __syncthreads();

    // scatter M into A-fragment layout: lane holds M[v=mt*16+(l&15)][k=(l>>4)*8+j]
    for (int g = tid; g < 16 * 64; g += 256) {
        const int mt = g >> 6, l2 = g & 63;
        const int v = mt * 16 + (l2 & 15);
        unsigned short o[8];
#pragma unroll
        for (int j = 0; j < 8; ++j) {
            const int k = (l2 >> 4) * 8 + j;
            o[j] = (k < NA) ? MT[k * 264 + v] : (unsigned short)0;
        }
        uint4 pk;
        pk.x = o[0] | ((unsigned)o[1] << 16); pk.y = o[2] | ((unsigned)o[3] << 16);
        pk.z = o[4] | ((unsigned)o[5] << 16); pk.w = o[6] | ((unsigned)o[7] << 16);
        *reinterpret_cast<uint4*>(wsM + ((size_t)(t * 16 + mt) * 64 + l2) * 8) = pk;
    }
}

// ---- main kernel: h = M_t * delta ------------------------------------------
// Identical to round 14 EXCEPT: plain f32x4 stores (nt removed — A/B test).
__global__ __launch_bounds__(512, 4) void residues_main(
    const float* __restrict__ x, const unsigned short* __restrict__ wsM,
    const int* __restrict__ type_ids, const int* __restrict__ res_idx,
    float* __restrict__ out, int n_atoms)
{
    const int tid = threadIdx.x, lane = tid & 63, w = tid >> 6;
    const int r = blockIdx.x >> 3;
    const int b0 = (blockIdx.x & 7) * 16;
    const int ri = res_idx[r], t = type_ids[r];

    __shared__ __align__(16) unsigned short dltT[48 * 40];   // 3840 B
    __shared__ __align__(16) float fstc[24 * 260];           // 24960 B

    // A-frags of M (depend only on t): wave w -> m-tiles 2w, 2w+1
    short8 aM[2];
#pragma unroll
    for (int mi = 0; mi < 2; ++mi)
        aM[mi] = *reinterpret_cast<const short8*>(wsM + ((size_t)(t * 16 + w * 2 + mi) * 64 + lane) * 8);

    // ---- stage: dltT (bf16, K padded to 32) + pos_ca -----------------------
    {
        const int bl = tid >> 5, k = tid & 31;     // 512 tasks = 16 bl x 32 k
        const float* xb = x + (size_t)(b0 + bl) * n_atoms * 3;
        if (k < 16) {
            int atom = ri + k; if (atom > n_atoms - 1) atom = n_atoms - 1;
            const float* src  = xb + (size_t)atom * 3;
            const float* root = xb + (size_t)(ri + 1) * 3;
#pragma unroll
            for (int c = 0; c < 3; ++c)
                dltT[(bl * 3 + c) * 40 + k] = f2bf(src[c] - root[c]);
            if (k == 1) {
#pragma unroll
                for (int c = 0; c < 3; ++c)
                    out[((size_t)(b0 + bl) * NR + r) * 3 + c] = root[c];
            }
        } else {
#pragma unroll
            for (int c = 0; c < 3; ++c)
                dltT[(bl * 3 + c) * 40 + k] = 0;
        }
    }
    __syncthreads();                               // B1: dltT ready

    // ---- single GEMM: K=32 (zeros >=14 in BOTH operands kill clamp rows) ---
    f32x4 acc[2][3];
#pragma unroll
    for (int mi = 0; mi < 2; ++mi)
#pragma unroll
        for (int ni = 0; ni < 3; ++ni) acc[mi][ni] = f32x4{0.f, 0.f, 0.f, 0.f};
    {
        short8 bf[3];
#pragma unroll
        for (int ni = 0; ni < 3; ++ni)
            bf[ni] = *reinterpret_cast<const short8*>(&dltT[(ni * 16 + (lane & 15)) * 40 + (lane >> 4) * 8]);
#pragma unroll
        for (int mi = 0; mi < 2; ++mi)
#pragma unroll
            for (int ni = 0; ni < 3; ++ni)
                acc[mi][ni] = __builtin_amdgcn_mfma_f32_16x16x32_bf16(aM[mi], bf[ni], acc[mi][ni], 0, 0, 0);
    }

    // ---- epilogue: 2 column-half passes, PLAIN f32x4 stores ----------------
    float* outh = out + (size_t)NB * NR * 3;
#pragma unroll 1
    for (int q = 0; q < 2; ++q) {
#pragma unroll
        for (int mi = 0; mi < 2; ++mi)
#pragma unroll
            for (int ni = 0; ni < 3; ++ni) {
                const int n = ni * 16 + (lane & 15);
                const int nloc = n - 24 * q;
                if (nloc >= 0 && nloc < 24) {
                    const int vb = w * 32 + mi * 16 + (lane >> 4) * 4;
                    *reinterpret_cast<f32x4*>(&fstc[nloc * 260 + vswz(vb)]) = acc[mi][ni];
                }
            }
        __syncthreads();                           // fstc ready
        {
            const size_t obase = ((size_t)(b0 + 8 * q + w) * NR + r) * (ND * 3);
#pragma unroll
            for (int i = 0; i < 3; ++i) {
                const int f0 = (lane + 64 * i) * 4;        // 0..764 step 4
                int v = f0 / 3;
                int c = f0 - v * 3;
                f32x4 o;
#pragma unroll
                for (int e = 0; e < 4; ++e) {
                    o[e] = fstc[(w * 3 + c) * 260 + vswz(v)];
                    ++c; if (c == 3) { c = 0; ++v; }
                }
                *reinterpret_cast<f32x4*>(&outh[obase + f0]) = o;   // plain store
            }
        }
        if (q == 0) __syncthreads();               // fstc reads done before overwrite
    }
}

// ---- fallback (round-2 verified VALU kernel) if ws too small ---------------
__global__ __launch_bounds__(256, 3) void residues_fused_fb(
    const float* __restrict__ x, const float* __restrict__ W0,
    const float* __restrict__ Wh, const int* __restrict__ type_ids,
    const int* __restrict__ res_idx, float* __restrict__ out, int n_atoms)
{
    const int tid = threadIdx.x;
    const int r = blockIdx.x >> 4;
    const int b0 = (blockIdx.x & 15) * 8;
    const int ri = res_idx[r], t = type_ids[r];
    __shared__ float dlt[NA][24];
    __shared__ float hA[ND][24];
    __shared__ float hB[ND][24];
    for (int idx = tid; idx < 8 * NA * 3; idx += 256) {
        const int bb = idx / (NA * 3), rem = idx % (NA * 3);
        const int a = rem / 3, c = rem % 3, b = b0 + bb;
        int ca = ri + a; if (ca > n_atoms - 1) ca = n_atoms - 1;
        const float root = x[((size_t)b * n_atoms + (ri + 1)) * 3 + c];
        dlt[a][bb * 3 + c] = x[((size_t)b * n_atoms + ca) * 3 + c] - root;
        if (a == 0) out[((size_t)b * NR + r) * 3 + c] = root;
    }
    __syncthreads();
    {
        const float* w0row = W0 + ((size_t)t * ND + tid) * NA;
        float acc[24];
#pragma unroll
        for (int n = 0; n < 24; ++n) acc[n] = 0.f;
#pragma unroll
        for (int a = 0; a < NA; ++a) {
            const float wv = w0row[a];
#pragma unroll
            for (int n = 0; n < 24; ++n) acc[n] += wv * dlt[a][n];
        }
#pragma unroll
        for (int n = 0; n < 24; ++n) hA[tid][n] = acc[n];
    }
    __syncthreads();
    const float* whbase = Wh + (size_t)t * 2 * ND * ND;
#pragma unroll
    for (int l = 0; l < 2; ++l) {
        const float* wrow = whbase + ((size_t)l * ND + tid) * ND;
        const float (*hin)[24] = (l == 0) ? hA : hB;
        float (*hout)[24]      = (l == 0) ? hB : hA;
        float acc[24];
#pragma unroll
        for (int n = 0; n < 24; ++n) acc[n] = 0.f;
        for (int u = 0; u < ND; ++u) {
            const float wv = wrow[u];
#pragma unroll
            for (int n = 0; n < 24; ++n) acc[n] += wv * hin[u][n];
        }
#pragma unroll
        for (int n = 0; n < 24; ++n) hout[tid][n] = acc[n];
        __syncthreads();
    }
    float* outh = out + (size_t)NB * NR * 3;
#pragma unroll
    for (int bb = 0; bb < 8; ++bb) {
        const size_t base = ((size_t)((b0 + bb) * NR + r)) * (ND * 3);
#pragma unroll
        for (int it = 0; it < 3; ++it) {
            const int g = it * 256 + tid;
            outh[base + g] = hA[g / 3][bb * 3 + g % 3];
        }
    }
}

extern "C" void kernel_launch(void* const* d_in, const int* in_sizes, int n_in,
                              void* d_out, int out_size, void* d_ws, size_t ws_size,
                              hipStream_t stream) {
    const float* x        = (const float*)d_in[0];
    const float* W0       = (const float*)d_in[1];
    const float* Wh       = (const float*)d_in[2];
    const int*   type_ids = (const int*)d_in[3];
    const int*   res_idx  = (const int*)d_in[4];
    float* out = (float*)d_out;
    const int n_atoms = in_sizes[0] / (NB * 3);

    if (ws_size >= WS_NEEDED) {
        unsigned short* wsM = (unsigned short*)d_ws;
        fold_M<<<NT, 256, 0, stream>>>(W0, Wh, wsM);
        residues_main<<<NR * 8, 512, 0, stream>>>(x, wsM, type_ids, res_idx, out, n_atoms);
    } else {
        residues_fused_fb<<<NR * 16, 256, 0, stream>>>(x, W0, Wh, type_ids, res_idx, out, n_atoms);
    }
}